// Round 6
// baseline (1171.955 us; speedup 1.0000x reference)
//
#include <hip/hip_runtime.h>
#include <cstdint>

#define DIM   128
#define NH    4
#define WSZ   7
#define NTOK  49
#define SHIFT 3
#define HIMG  56
#define BATCH 64
#define LTOK  3136
#define HID   512
#define EPSF  1e-5f

typedef short bf16x8 __attribute__((ext_vector_type(8)));
typedef float f32x4  __attribute__((ext_vector_type(4)));

__device__ __forceinline__ float bf2f(ushort u){ return __uint_as_float(((uint32_t)u)<<16); }
__device__ __forceinline__ ushort f2bf(float f){
  uint32_t u = __float_as_uint(f);
  u += 0x7FFFu + ((u>>16)&1u);
  return (ushort)(u>>16);
}
__device__ __forceinline__ float wred(float v){
  #pragma unroll
  for (int off=32; off; off>>=1) v += __shfl_xor(v, off, 64);
  return v;
}
// Build MFMA B-fragment from row-major f32 weight W[K][N]: lane needs W[k0+j][n], j=0..7
__device__ __forceinline__ bf16x8 load_wfrag(const float* __restrict__ W, int ld, int k0, int n){
  bf16x8 f;
  #pragma unroll
  for (int j=0;j<8;j++) f[j] = (short)f2bf(W[(size_t)(k0+j)*ld + n]);
  return f;
}

// ---------------- K_A: LN1 + shift + window + QKV + attention + proj + residual ----------------
__global__ __launch_bounds__(256) void swin_attn_kernel(
    const float* __restrict__ x, const float* __restrict__ n1g, const float* __restrict__ n1b,
    const float* __restrict__ qkvw, const float* __restrict__ qkvb,
    const float* __restrict__ bias_tbl, const float* __restrict__ pw,
    const float* __restrict__ projb, float* __restrict__ x2)
{
  __shared__ ushort bufA[64][136];        // xw (LN'd window), later attn_out
  __shared__ ushort qkvs[12*NTOK*32];     // [(which*4+head)*49 + n]*32 + d
  __shared__ float  tblf[169*4];

  const int tid  = threadIdx.x;
  const int wave = tid >> 6;
  const int lane = tid & 63;
  const int b_   = blockIdx.x;
  const int b    = b_ >> 6;
  const int win  = b_ & 63;
  const int wi   = win >> 3, wj = win & 7;

  for (int i = tid; i < 676; i += 256) tblf[i] = bias_tbl[i];
  for (int i = tid; i < 15*136; i += 256) bufA[49 + i/136][i%136] = 0;

  // ---- Phase 0: LN1 on gathered (shifted) window rows ----
  for (int r = wave; r < NTOK; r += 4){
    int ti = r / 7, tj = r % 7;
    int hh = (wi*7 + ti + SHIFT) % HIMG;
    int ww = (wj*7 + tj + SHIFT) % HIMG;
    size_t base = ((size_t)b * LTOK + hh*HIMG + ww) * DIM;
    int c = lane*2;
    float2 tv = *(const float2*)(x + base + c);
    float v0 = tv.x, v1 = tv.y;
    float mu = wred(v0 + v1) * (1.0f/128.0f);
    float d0 = v0-mu, d1 = v1-mu;
    float rstd = rsqrtf(wred(d0*d0 + d1*d1)*(1.0f/128.0f) + EPSF);
    bufA[r][c]   = f2bf(d0*rstd*n1g[c]   + n1b[c]);
    bufA[r][c+1] = f2bf(d1*rstd*n1g[c+1] + n1b[c+1]);
  }
  __syncthreads();

  const int ncol  = lane & 15;
  const int koff  = (lane >> 4) * 8;
  const int rbase = (lane >> 4) * 4;

  // ---- Phase 1: QKV GEMM (64x384, K=128) ----
  {
    bf16x8 afrag[4][4];
    #pragma unroll
    for (int mt=0; mt<4; mt++)
      #pragma unroll
      for (int kb=0; kb<4; kb++)
        afrag[mt][kb] = *(const bf16x8*)&bufA[mt*16 + ncol][kb*32 + koff];

    #pragma unroll
    for (int nt=0; nt<6; nt++){
      int cn = wave*96 + nt*16;
      int which = cn >> 7;
      int head  = (cn >> 5) & 3;
      int d0    = (cn & 31) + ncol;
      bf16x8 bfrag[4];
      #pragma unroll
      for (int kb=0; kb<4; kb++) bfrag[kb] = load_wfrag(qkvw, 384, kb*32 + koff, cn + ncol);
      float bias = qkvb[cn + ncol];
      #pragma unroll
      for (int mt=0; mt<4; mt++){
        f32x4 acc = {0.f,0.f,0.f,0.f};
        #pragma unroll
        for (int kb=0; kb<4; kb++)
          acc = __builtin_amdgcn_mfma_f32_16x16x32_bf16(afrag[mt][kb], bfrag[kb], acc, 0,0,0);
        #pragma unroll
        for (int r=0; r<4; r++){
          int m = mt*16 + rbase + r;
          if (m < NTOK)
            qkvs[((which*4 + head)*NTOK + m)*32 + d0] = f2bf(acc[r] + bias);
        }
      }
    }
  }
  __syncthreads();

  // ---- Phase 2: per-head attention (wave = head, lane = query row) ----
  {
    const int h = wave;
    const int n = lane;
    const int ne = (n < NTOK) ? n : 0;   // clamp for lanes 49..63 (results discarded)
    int ti = ne/7, tj = ne%7;
    int habs = wi*7 + ti, wabs = wj*7 + tj;
    int rn = (habs<49?0:(habs<53?1:2))*3 + (wabs<49?0:(wabs<53?1:2));

    float qf[32];
    {
      const ushort* qp = &qkvs[((0*4+h)*NTOK + ne)*32];
      #pragma unroll
      for (int i=0;i<4;i++){
        bf16x8 v = *(const bf16x8*)(qp + i*8);
        #pragma unroll
        for (int j=0;j<8;j++) qf[i*8+j] = bf2f((ushort)v[j]);
      }
    }

    float p[49];
    const float scale = 0.17677669529663687f;   // 1/sqrt(32)
    #pragma unroll
    for (int m=0; m<49; m++){
      const ushort* kp = &qkvs[((1*4+h)*NTOK + m)*32];
      float s = 0.f;
      #pragma unroll
      for (int i=0;i<4;i++){
        bf16x8 v = *(const bf16x8*)(kp + i*8);
        #pragma unroll
        for (int j=0;j<8;j++) s += qf[i*8+j]*bf2f((ushort)v[j]);
      }
      const int si = m/7, sj = m%7;
      int idx = (ti - si + 6)*13 + (tj - sj + 6);
      float bias = tblf[idx*4 + h];
      int sh = wi*7 + si, sw = wj*7 + sj;
      int rm = (sh<49?0:(sh<53?1:2))*3 + (sw<49?0:(sw<53?1:2));
      p[m] = s*scale + bias + (rn == rm ? 0.f : -100.f);
    }

    float mx = p[0];
    #pragma unroll
    for (int m=1;m<49;m++) mx = fmaxf(mx, p[m]);
    float sum = 0.f;
    #pragma unroll
    for (int m=0;m<49;m++){ p[m] = __expf(p[m]-mx); sum += p[m]; }
    float rs = 1.0f/sum;

    float of[32];
    #pragma unroll
    for (int d=0;d<32;d++) of[d]=0.f;
    #pragma unroll
    for (int m=0;m<49;m++){
      const ushort* vp = &qkvs[((2*4+h)*NTOK + m)*32];
      float pm = p[m]*rs;
      #pragma unroll
      for (int i=0;i<4;i++){
        bf16x8 v = *(const bf16x8*)(vp + i*8);
        #pragma unroll
        for (int j=0;j<8;j++) of[i*8+j] += pm*bf2f((ushort)v[j]);
      }
    }
    if (n < NTOK){
      #pragma unroll
      for (int i=0;i<4;i++){
        ushort tmp[8];
        #pragma unroll
        for (int j=0;j<8;j++) tmp[j] = f2bf(of[i*8+j]);
        *(bf16x8*)&bufA[n][h*32 + i*8] = *(const bf16x8*)tmp;
      }
    }
  }
  __syncthreads();

  // ---- Phase 3: proj GEMM (64x128, K=128) + un-shift scatter + residual (f32 out) ----
  {
    bf16x8 afrag[4][4];
    #pragma unroll
    for (int mt=0; mt<4; mt++)
      #pragma unroll
      for (int kb=0; kb<4; kb++)
        afrag[mt][kb] = *(const bf16x8*)&bufA[mt*16 + ncol][kb*32 + koff];

    #pragma unroll
    for (int nt=0; nt<2; nt++){
      int cn = wave*32 + nt*16;
      int j = cn + ncol;
      bf16x8 bfrag[4];
      #pragma unroll
      for (int kb=0; kb<4; kb++) bfrag[kb] = load_wfrag(pw, 128, kb*32 + koff, j);
      float bias = projb[j];
      #pragma unroll
      for (int mt=0; mt<4; mt++){
        f32x4 acc = {0.f,0.f,0.f,0.f};
        #pragma unroll
        for (int kb=0; kb<4; kb++)
          acc = __builtin_amdgcn_mfma_f32_16x16x32_bf16(afrag[mt][kb], bfrag[kb], acc, 0,0,0);
        #pragma unroll
        for (int r=0; r<4; r++){
          int m = mt*16 + rbase + r;
          if (m < NTOK){
            int ti = m/7, tj = m%7;
            int hh = (wi*7 + ti + SHIFT) % HIMG;
            int ww = (wj*7 + tj + SHIFT) % HIMG;
            size_t addr = ((size_t)b*LTOK + hh*HIMG + ww)*DIM + j;
            x2[addr] = acc[r] + bias + x[addr];
          }
        }
      }
    }
  }
}

// ---------------- K_B: LN2 + fc1 + GELU + fc2 + residual (IN PLACE on x2=d_out, f32) ----------------
__global__ __launch_bounds__(256) void swin_mlp_kernel(
    const float* x2, const float* __restrict__ n2g, const float* __restrict__ n2b,
    const float* __restrict__ f1w, const float* __restrict__ fc1b,
    const float* __restrict__ f2w, const float* __restrict__ fc2b,
    float* out)
{
  __shared__ float  raw[32][132];
  __shared__ ushort xn[32][136];
  __shared__ ushort hb[32][520];
  const int tid = threadIdx.x, wave = tid>>6, lane = tid&63;
  const size_t row0 = (size_t)blockIdx.x * 32;

  // ---- LN2 ----
  #pragma unroll
  for (int i=0;i<8;i++){
    int r = wave + i*4;
    size_t base = (row0 + r)*DIM;
    int c = lane*2;
    float2 tv = *(const float2*)(x2 + base + c);
    float v0 = tv.x, v1 = tv.y;
    float mu = wred(v0+v1)*(1.f/128.f);
    float d0 = v0-mu, d1 = v1-mu;
    float rstd = rsqrtf(wred(d0*d0+d1*d1)*(1.f/128.f) + EPSF);
    raw[r][c]   = v0;
    raw[r][c+1] = v1;
    xn[r][c]   = f2bf(d0*rstd*n2g[c]   + n2b[c]);
    xn[r][c+1] = f2bf(d1*rstd*n2g[c+1] + n2b[c+1]);
  }
  __syncthreads();

  const int ncol  = lane & 15;
  const int koff  = (lane >> 4) * 8;
  const int rbase = (lane >> 4) * 4;

  // ---- fc1 + exact GELU ----
  {
    bf16x8 afrag[2][4];
    #pragma unroll
    for (int mt=0; mt<2; mt++)
      #pragma unroll
      for (int kb=0; kb<4; kb++)
        afrag[mt][kb] = *(const bf16x8*)&xn[mt*16 + ncol][kb*32 + koff];

    #pragma unroll
    for (int nt=0; nt<8; nt++){
      int cn = wave*128 + nt*16;
      bf16x8 bfrag[4];
      #pragma unroll
      for (int kb=0; kb<4; kb++) bfrag[kb] = load_wfrag(f1w, 512, kb*32 + koff, cn + ncol);
      float bias = fc1b[cn + ncol];
      #pragma unroll
      for (int mt=0; mt<2; mt++){
        f32x4 acc = {0.f,0.f,0.f,0.f};
        #pragma unroll
        for (int kb=0; kb<4; kb++)
          acc = __builtin_amdgcn_mfma_f32_16x16x32_bf16(afrag[mt][kb], bfrag[kb], acc, 0,0,0);
        #pragma unroll
        for (int r=0; r<4; r++){
          int m = mt*16 + rbase + r;
          float v = acc[r] + bias;
          float g = 0.5f*v*(1.0f + erff(v*0.70710678118654752f));
          hb[m][cn + ncol] = f2bf(g);
        }
      }
    }
  }
  __syncthreads();

  // ---- fc2 + residual (f32 out) ----
  {
    #pragma unroll
    for (int nt=0; nt<2; nt++){
      int cn = wave*32 + nt*16;
      int j = cn + ncol;
      float bias = fc2b[j];
      bf16x8 bfrag[16];
      #pragma unroll
      for (int kb=0; kb<16; kb++)
        bfrag[kb] = load_wfrag(f2w, 128, kb*32 + koff, j);
      #pragma unroll
      for (int mt=0; mt<2; mt++){
        f32x4 acc = {0.f,0.f,0.f,0.f};
        #pragma unroll
        for (int kb=0; kb<16; kb++){
          bf16x8 a = *(const bf16x8*)&hb[mt*16 + ncol][kb*32 + koff];
          acc = __builtin_amdgcn_mfma_f32_16x16x32_bf16(a, bfrag[kb], acc, 0,0,0);
        }
        #pragma unroll
        for (int r=0; r<4; r++){
          int m = mt*16 + rbase + r;
          out[(row0 + m)*DIM + j] = acc[r] + bias + raw[m][j];
        }
      }
    }
  }
}

extern "C" void kernel_launch(void* const* d_in, const int* in_sizes, int n_in,
                              void* d_out, int out_size, void* d_ws, size_t ws_size,
                              hipStream_t stream)
{
  const float* x    = (const float*)d_in[0];
  const float* n1g  = (const float*)d_in[1];
  const float* n1b  = (const float*)d_in[2];
  const float* qkvw = (const float*)d_in[3];
  const float* qkvb = (const float*)d_in[4];
  const float* tbl  = (const float*)d_in[5];
  const float* pw   = (const float*)d_in[6];
  const float* pb   = (const float*)d_in[7];
  const float* n2g  = (const float*)d_in[8];
  const float* n2b  = (const float*)d_in[9];
  const float* f1w  = (const float*)d_in[10];
  const float* f1b  = (const float*)d_in[11];
  const float* f2w  = (const float*)d_in[12];
  const float* f2b  = (const float*)d_in[13];

  // f32 everywhere at the interface. x2 (post-attention residual) lives in d_out;
  // MLP runs in place on it. No workspace usage.
  float* x2 = (float*)d_out;

  swin_attn_kernel<<<4096, 256, 0, stream>>>(x, n1g, n1b, qkvw, qkvb, tbl,
                                             pw, pb, x2);
  swin_mlp_kernel<<<6272, 256, 0, stream>>>(x2, n2g, n2b, f1w, f1b,
                                            f2w, f2b, (float*)d_out);
}

// Round 7
// 649.051 us; speedup vs baseline: 1.8056x; 1.8056x over previous
//
#include <hip/hip_runtime.h>
#include <cstdint>

#define DIM   128
#define NH    4
#define WSZ   7
#define NTOK  49
#define SHIFT 3
#define HIMG  56
#define BATCH 64
#define LTOK  3136
#define HID   512
#define EPSF  1e-5f

typedef short bf16x8 __attribute__((ext_vector_type(8)));
typedef float f32x4  __attribute__((ext_vector_type(4)));

__device__ __forceinline__ float bf2f(ushort u){ return __uint_as_float(((uint32_t)u)<<16); }
__device__ __forceinline__ ushort f2bf(float f){
  uint32_t u = __float_as_uint(f);
  u += 0x7FFFu + ((u>>16)&1u);
  return (ushort)(u>>16);
}
__device__ __forceinline__ float wred(float v){
  #pragma unroll
  for (int off=32; off; off>>=1) v += __shfl_xor(v, off, 64);
  return v;
}

// ------------- weight transpose+convert: dst[c*R + r] = bf16(src[r*C + c]) -------------
__global__ void transpose_cvt(const float* __restrict__ src, ushort* __restrict__ dst,
                              int R, int Cc){
  int idx = blockIdx.x*256 + threadIdx.x;
  if (idx < R*Cc){
    int r = idx / Cc, c = idx % Cc;
    dst[(size_t)c*R + r] = f2bf(src[idx]);
  }
}

// LDS layout (ushort units), single block to make overlay/spill reads well-defined:
//   [0, 8192)                bufA[64][128]   LN'd window, later attn-out
//   [8192, 20736)            qk[h][w][49][32]  (w: 0=Q,1=K); P overlays per-head at stride 56
//   [20736, 29952)           vt[h][32][72]   V^T [dim][token], tokens 49.. zeroed
//   [29952, 30628)           tblb[169*4]     rel-bias table bf16
#define OFF_BUFA 0
#define OFF_QK   8192
#define OFF_VT   20736
#define OFF_TBL  29952
#define SMEM_SZ  30628

// ---------------- K_A: LN1 + shift + window + QKV + MFMA attention + proj + residual ----------------
__global__ __launch_bounds__(256,2) void swin_attn_kernel(
    const float* __restrict__ x, const float* __restrict__ n1g, const float* __restrict__ n1b,
    const ushort* __restrict__ qkv_wt, const float* __restrict__ qkvb,
    const float* __restrict__ bias_tbl, const ushort* __restrict__ proj_wt,
    const float* __restrict__ projb, float* __restrict__ x2)
{
  __shared__ ushort smem[SMEM_SZ];

  const int tid  = threadIdx.x;
  const int wave = tid >> 6;
  const int lane = tid & 63;
  const int b_   = blockIdx.x;
  const int b    = b_ >> 6;
  const int win  = b_ & 63;
  const int wi   = win >> 3, wj = win & 7;

  const int ncol  = lane & 15;
  const int quad  = lane >> 4;
  const int koff  = quad * 8;
  const int rbase = quad * 4;

  // ---- init: zero V^T (tokens 49.. must be 0 for PV), zero bufA rows 49-63, load bias tbl ----
  for (int i = tid; i < NH*32*72; i += 256) smem[OFF_VT + i] = 0;
  for (int i = tid; i < 676; i += 256) smem[OFF_TBL + i] = f2bf(bias_tbl[i]);
  for (int i = tid; i < 15*128; i += 256) smem[OFF_BUFA + (49 + i/128)*128 + (i%128)] = 0;

  // ---- Phase 0: LN1 on gathered (shifted) window rows ----
  for (int r = wave; r < NTOK; r += 4){
    int ti = r / 7, tj = r % 7;
    int hh = (wi*7 + ti + SHIFT) % HIMG;
    int ww = (wj*7 + tj + SHIFT) % HIMG;
    size_t base = ((size_t)b * LTOK + hh*HIMG + ww) * DIM;
    int c = lane*2;
    float2 tv = *(const float2*)(x + base + c);
    float v0 = tv.x, v1 = tv.y;
    float mu = wred(v0 + v1) * (1.0f/128.0f);
    float d0 = v0-mu, d1 = v1-mu;
    float rstd = rsqrtf(wred(d0*d0 + d1*d1)*(1.0f/128.0f) + EPSF);
    smem[OFF_BUFA + r*128 + c]   = f2bf(d0*rstd*n1g[c]   + n1b[c]);
    smem[OFF_BUFA + r*128 + c+1] = f2bf(d1*rstd*n1g[c+1] + n1b[c+1]);
  }
  __syncthreads();

  // ---- Phase 1: QKV GEMM (64x384, K=128), weights pre-transposed bf16 [384][128] ----
  {
    bf16x8 afrag[4][4];
    #pragma unroll
    for (int mt=0; mt<4; mt++)
      #pragma unroll
      for (int kb=0; kb<4; kb++)
        afrag[mt][kb] = *(const bf16x8*)&smem[OFF_BUFA + (mt*16 + ncol)*128 + kb*32 + koff];

    #pragma unroll
    for (int nt=0; nt<6; nt++){
      int c = wave*96 + nt*16 + ncol;
      int which = c >> 7, head = (c >> 5) & 3, d = c & 31;
      bf16x8 bfrag[4];
      #pragma unroll
      for (int kb=0; kb<4; kb++) bfrag[kb] = *(const bf16x8*)(qkv_wt + (size_t)c*128 + kb*32 + koff);
      float bias = qkvb[c];
      #pragma unroll
      for (int mt=0; mt<4; mt++){
        f32x4 acc = {0.f,0.f,0.f,0.f};
        #pragma unroll
        for (int kb=0; kb<4; kb++)
          acc = __builtin_amdgcn_mfma_f32_16x16x32_bf16(afrag[mt][kb], bfrag[kb], acc, 0,0,0);
        #pragma unroll
        for (int r=0; r<4; r++){
          int m = mt*16 + rbase + r;
          if (m < NTOK){
            ushort v = f2bf(acc[r] + bias);
            if (which == 2) smem[OFF_VT + (head*32 + d)*72 + m] = v;
            else            smem[OFF_QK + ((head*2 + which)*NTOK + m)*32 + d] = v;
          }
        }
      }
    }
  }
  __syncthreads();

  // ---- Phase 2: MFMA attention, wave = head ----
  {
    const int h = wave;
    const int qbase = OFF_QK + (h*2    )*NTOK*32;
    const int kbase = OFF_QK + (h*2 + 1)*NTOK*32;
    const int pbase = qbase;                       // P overlays Q+K region (dead after S)

    bf16x8 qf[4], kf[4];
    #pragma unroll
    for (int mt=0; mt<4; mt++) qf[mt] = *(const bf16x8*)&smem[qbase + (mt*16 + ncol)*32 + koff];
    #pragma unroll
    for (int nt=0; nt<4; nt++) kf[nt] = *(const bf16x8*)&smem[kbase + (nt*16 + ncol)*32 + koff];

    f32x4 s[4][4];
    #pragma unroll
    for (int mt=0; mt<4; mt++)
      #pragma unroll
      for (int nt=0; nt<4; nt++){
        f32x4 z = {0.f,0.f,0.f,0.f};
        s[mt][nt] = __builtin_amdgcn_mfma_f32_16x16x32_bf16(qf[mt], kf[nt], z, 0,0,0);
      }

    // per-lane column (key) properties
    int kcol[4], rm[4]; float kb_ok[4];
    #pragma unroll
    for (int nt=0; nt<4; nt++){
      int k = nt*16 + ncol;
      kcol[nt] = k;
      int kc = k < NTOK ? k : 48;
      int si = kc/7, sj = kc%7;
      int sh = wi*7 + si, sw = wj*7 + sj;
      rm[nt] = (sh<49?0:(sh<53?1:2))*3 + (sw<49?0:(sw<53?1:2));
      kb_ok[nt] = (float)si;   // reuse: store si in low bits? keep separate below
    }
    const float scale = 0.17677669529663687f;  // 1/sqrt(32)

    // fixup + softmax (rows live in 16-lane shuffle groups)
    #pragma unroll
    for (int mt=0; mt<4; mt++){
      #pragma unroll
      for (int r=0; r<4; r++){
        int m  = mt*16 + rbase + r;
        int mc = m < NTOK ? m : 48;
        int ti = mc/7, tj = mc%7;
        int habs = wi*7 + ti, wabs = wj*7 + tj;
        int rn = (habs<49?0:(habs<53?1:2))*3 + (wabs<49?0:(wabs<53?1:2));
        float sv[4];
        #pragma unroll
        for (int nt=0; nt<4; nt++){
          int k  = kcol[nt];
          int kc = k < NTOK ? k : 48;
          int si = kc/7, sj = kc%7;
          int idx = (ti - si + 6)*13 + (tj - sj + 6);
          float bias = bf2f(smem[OFF_TBL + idx*4 + h]);
          float v = s[mt][nt][r]*scale + bias + (rn == rm[nt] ? 0.f : -100.f);
          sv[nt] = (k < NTOK) ? v : -1e30f;
        }
        float mx = fmaxf(fmaxf(sv[0],sv[1]), fmaxf(sv[2],sv[3]));
        #pragma unroll
        for (int off=1; off<16; off<<=1) mx = fmaxf(mx, __shfl_xor(mx, off, 64));
        float sum = 0.f;
        #pragma unroll
        for (int nt=0; nt<4; nt++){ sv[nt] = __expf(sv[nt]-mx); sum += sv[nt]; }
        #pragma unroll
        for (int off=1; off<16; off<<=1) sum += __shfl_xor(sum, off, 64);
        float rs = 1.0f/sum;
        #pragma unroll
        for (int nt=0; nt<4; nt++) s[mt][nt][r] = sv[nt]*rs;
      }
    }

    // write P (bf16, stride 56) — only valid rows, cols < 56 (cols>=49 multiply zeroed V)
    #pragma unroll
    for (int mt=0; mt<4; mt++)
      #pragma unroll
      for (int r=0; r<4; r++){
        int m = mt*16 + rbase + r;
        if (m < NTOK){
          #pragma unroll
          for (int nt=0; nt<4; nt++){
            int k = kcol[nt];
            if (k < 56) smem[pbase + m*56 + k] = f2bf(s[mt][nt][r]);
          }
        }
      }
    __builtin_amdgcn_s_waitcnt(0);   // ensure own ds writes visible before reads (lgkmcnt 0)

    // PV: A = P [64x64], B = V^T rows=dim
    bf16x8 vf[2][2], pf;
    #pragma unroll
    for (int nt=0; nt<2; nt++)
      #pragma unroll
      for (int kq=0; kq<2; kq++)
        vf[nt][kq] = *(const bf16x8*)&smem[OFF_VT + (h*32 + nt*16 + ncol)*72 + kq*32 + koff];

    f32x4 o[4][2];
    #pragma unroll
    for (int mt=0; mt<4; mt++)
      #pragma unroll
      for (int nt=0; nt<2; nt++){ f32x4 z={0.f,0.f,0.f,0.f}; o[mt][nt]=z; }

    #pragma unroll
    for (int mt=0; mt<4; mt++)
      #pragma unroll
      for (int kq=0; kq<2; kq++){
        pf = *(const bf16x8*)&smem[pbase + (mt*16 + ncol)*56 + kq*32 + koff];
        #pragma unroll
        for (int nt=0; nt<2; nt++)
          o[mt][nt] = __builtin_amdgcn_mfma_f32_16x16x32_bf16(pf, vf[nt][kq], o[mt][nt], 0,0,0);
      }

    #pragma unroll
    for (int mt=0; mt<4; mt++)
      #pragma unroll
      for (int nt=0; nt<2; nt++)
        #pragma unroll
        for (int r=0; r<4; r++){
          int m = mt*16 + rbase + r;
          if (m < NTOK)
            smem[OFF_BUFA + m*128 + h*32 + nt*16 + ncol] = f2bf(o[mt][nt][r]);
        }
  }
  __syncthreads();

  // ---- Phase 3: proj GEMM (64x128, K=128) + un-shift scatter + residual (f32 out) ----
  {
    bf16x8 afrag[4][4];
    #pragma unroll
    for (int mt=0; mt<4; mt++)
      #pragma unroll
      for (int kb=0; kb<4; kb++)
        afrag[mt][kb] = *(const bf16x8*)&smem[OFF_BUFA + (mt*16 + ncol)*128 + kb*32 + koff];

    #pragma unroll
    for (int nt=0; nt<2; nt++){
      int j = wave*32 + nt*16 + ncol;
      bf16x8 bfrag[4];
      #pragma unroll
      for (int kb=0; kb<4; kb++) bfrag[kb] = *(const bf16x8*)(proj_wt + (size_t)j*128 + kb*32 + koff);
      float bias = projb[j];
      #pragma unroll
      for (int mt=0; mt<4; mt++){
        f32x4 acc = {0.f,0.f,0.f,0.f};
        #pragma unroll
        for (int kb=0; kb<4; kb++)
          acc = __builtin_amdgcn_mfma_f32_16x16x32_bf16(afrag[mt][kb], bfrag[kb], acc, 0,0,0);
        #pragma unroll
        for (int r=0; r<4; r++){
          int m = mt*16 + rbase + r;
          if (m < NTOK){
            int ti = m/7, tj = m%7;
            int hh = (wi*7 + ti + SHIFT) % HIMG;
            int ww = (wj*7 + tj + SHIFT) % HIMG;
            size_t addr = ((size_t)b*LTOK + hh*HIMG + ww)*DIM + j;
            x2[addr] = acc[r] + bias + x[addr];
          }
        }
      }
    }
  }
}

// ---------------- K_B: LN2 + fc1 + GELU + fc2 + residual (IN PLACE on x2=d_out, f32) ----------------
__global__ __launch_bounds__(256) void swin_mlp_kernel(
    const float* x2, const float* __restrict__ n2g, const float* __restrict__ n2b,
    const ushort* __restrict__ fc1_wt, const float* __restrict__ fc1b,
    const ushort* __restrict__ fc2_wt, const float* __restrict__ fc2b,
    float* out)
{
  __shared__ float  raw[32][132];
  __shared__ ushort xn[32][136];
  __shared__ ushort hb[32][520];
  const int tid = threadIdx.x, wave = tid>>6, lane = tid&63;
  const size_t row0 = (size_t)blockIdx.x * 32;

  // ---- LN2 ----
  #pragma unroll
  for (int i=0;i<8;i++){
    int r = wave + i*4;
    size_t base = (row0 + r)*DIM;
    int c = lane*2;
    float2 tv = *(const float2*)(x2 + base + c);
    float v0 = tv.x, v1 = tv.y;
    float mu = wred(v0+v1)*(1.f/128.f);
    float d0 = v0-mu, d1 = v1-mu;
    float rstd = rsqrtf(wred(d0*d0+d1*d1)*(1.f/128.f) + EPSF);
    raw[r][c]   = v0;
    raw[r][c+1] = v1;
    xn[r][c]   = f2bf(d0*rstd*n2g[c]   + n2b[c]);
    xn[r][c+1] = f2bf(d1*rstd*n2g[c+1] + n2b[c+1]);
  }
  __syncthreads();

  const int ncol  = lane & 15;
  const int koff  = (lane >> 4) * 8;
  const int rbase = (lane >> 4) * 4;

  // ---- fc1 + exact GELU ----
  {
    bf16x8 afrag[2][4];
    #pragma unroll
    for (int mt=0; mt<2; mt++)
      #pragma unroll
      for (int kb=0; kb<4; kb++)
        afrag[mt][kb] = *(const bf16x8*)&xn[mt*16 + ncol][kb*32 + koff];

    #pragma unroll
    for (int nt=0; nt<8; nt++){
      int cn = wave*128 + nt*16;
      bf16x8 bfrag[4];
      #pragma unroll
      for (int kb=0; kb<4; kb++)
        bfrag[kb] = *(const bf16x8*)(fc1_wt + (size_t)(cn + ncol)*128 + kb*32 + koff);
      float bias = fc1b[cn + ncol];
      #pragma unroll
      for (int mt=0; mt<2; mt++){
        f32x4 acc = {0.f,0.f,0.f,0.f};
        #pragma unroll
        for (int kb=0; kb<4; kb++)
          acc = __builtin_amdgcn_mfma_f32_16x16x32_bf16(afrag[mt][kb], bfrag[kb], acc, 0,0,0);
        #pragma unroll
        for (int r=0; r<4; r++){
          int m = mt*16 + rbase + r;
          float v = acc[r] + bias;
          float g = 0.5f*v*(1.0f + erff(v*0.70710678118654752f));
          hb[m][cn + ncol] = f2bf(g);
        }
      }
    }
  }
  __syncthreads();

  // ---- fc2 + residual (f32 out) ----
  {
    #pragma unroll
    for (int nt=0; nt<2; nt++){
      int j = wave*32 + nt*16 + ncol;
      float bias = fc2b[j];
      bf16x8 bfrag[16];
      #pragma unroll
      for (int kb=0; kb<16; kb++)
        bfrag[kb] = *(const bf16x8*)(fc2_wt + (size_t)j*512 + kb*32 + koff);
      #pragma unroll
      for (int mt=0; mt<2; mt++){
        f32x4 acc = {0.f,0.f,0.f,0.f};
        #pragma unroll
        for (int kb=0; kb<16; kb++){
          bf16x8 a = *(const bf16x8*)&hb[mt*16 + ncol][kb*32 + koff];
          acc = __builtin_amdgcn_mfma_f32_16x16x32_bf16(a, bfrag[kb], acc, 0,0,0);
        }
        #pragma unroll
        for (int r=0; r<4; r++){
          int m = mt*16 + rbase + r;
          out[(row0 + m)*DIM + j] = acc[r] + bias + raw[m][j];
        }
      }
    }
  }
}

extern "C" void kernel_launch(void* const* d_in, const int* in_sizes, int n_in,
                              void* d_out, int out_size, void* d_ws, size_t ws_size,
                              hipStream_t stream)
{
  const float* x    = (const float*)d_in[0];
  const float* n1g  = (const float*)d_in[1];
  const float* n1b  = (const float*)d_in[2];
  const float* qkvw = (const float*)d_in[3];
  const float* qkvb = (const float*)d_in[4];
  const float* tbl  = (const float*)d_in[5];
  const float* pw   = (const float*)d_in[6];
  const float* pb   = (const float*)d_in[7];
  const float* n2g  = (const float*)d_in[8];
  const float* n2b  = (const float*)d_in[9];
  const float* f1w  = (const float*)d_in[10];
  const float* f1b  = (const float*)d_in[11];
  const float* f2w  = (const float*)d_in[12];
  const float* f2b  = (const float*)d_in[13];

  // Workspace: transposed bf16 weights only (393,216 B).
  ushort* qkv_wt  = (ushort*)d_ws;            // [384][128]
  ushort* proj_wt = qkv_wt + 49152;           // [128][128]
  ushort* fc1_wt  = proj_wt + 16384;          // [512][128]
  ushort* fc2_wt  = fc1_wt + 65536;           // [128][512]

  transpose_cvt<<<(49152+255)/256, 256, 0, stream>>>(qkvw, qkv_wt, 128, 384);
  transpose_cvt<<<(16384+255)/256, 256, 0, stream>>>(pw,   proj_wt, 128, 128);
  transpose_cvt<<<(65536+255)/256, 256, 0, stream>>>(f1w,  fc1_wt, 128, 512);
  transpose_cvt<<<(65536+255)/256, 256, 0, stream>>>(f2w,  fc2_wt, 512, 128);

  // x2 (post-attention residual, f32) lives in d_out; MLP runs in place on it.
  float* x2 = (float*)d_out;

  swin_attn_kernel<<<4096, 256, 0, stream>>>(x, n1g, n1b, qkv_wt, qkvb, tbl,
                                             proj_wt, pb, x2);
  swin_mlp_kernel<<<6272, 256, 0, stream>>>(x2, n2g, n2b, fc1_wt, f1b,
                                            fc2_wt, f2b, (float*)d_out);
}

// Round 8
// 625.429 us; speedup vs baseline: 1.8738x; 1.0378x over previous
//
#include <hip/hip_runtime.h>
#include <cstdint>

#define DIM   128
#define NH    4
#define WSZ   7
#define NTOK  49
#define SHIFT 3
#define HIMG  56
#define BATCH 64
#define LTOK  3136
#define HID   512
#define EPSF  1e-5f

typedef short bf16x8 __attribute__((ext_vector_type(8)));
typedef float f32x4  __attribute__((ext_vector_type(4)));

__device__ __forceinline__ float bf2f(ushort u){ return __uint_as_float(((uint32_t)u)<<16); }
__device__ __forceinline__ ushort f2bf(float f){
  uint32_t u = __float_as_uint(f);
  u += 0x7FFFu + ((u>>16)&1u);
  return (ushort)(u>>16);
}
__device__ __forceinline__ float wred(float v){
  #pragma unroll
  for (int off=32; off; off>>=1) v += __shfl_xor(v, off, 64);
  return v;
}

// ------------- weight transpose+convert: dst[c*R + r] = bf16(src[r*C + c]) -------------
__global__ void transpose_cvt(const float* __restrict__ src, ushort* __restrict__ dst,
                              int R, int Cc){
  int idx = blockIdx.x*256 + threadIdx.x;
  if (idx < R*Cc){
    int r = idx / Cc, c = idx % Cc;
    dst[(size_t)c*R + r] = f2bf(src[idx]);
  }
}

// LDS layout (ushort units):
//   [OFF_BUFA, +8704)   bufA[64][136]  xw (LN1), attn-out, then xn (LN2)   (stride 136: 2-way only)
//   [OFF_QK,   +12544)  qk[h][{Q,K}][49][32] ; per-head P overlay (stride 56)
//                        MLP phase overlay: x2row f32[49][132] (12936 ush) then
//                        hchunk bf16[64][136] at OFF_QK+12936 (ends 30344 < OFF_TBL)
//   [OFF_VT,   +9216)   vt[h][32][72]  V^T [dim][token], tokens 49.. zeroed
//   [OFF_TBL,  +676)    rel-bias table bf16
#define OFF_BUFA 0
#define OFF_QK   8704
#define OFF_VT   21248
#define OFF_TBL  30464
#define SMEM_SZ  31140
#define OFF_HCH  (OFF_QK + 12936)

// ---------------- Fused: LN1 + shift/window + QKV + attention + proj + residual
//                        + LN2 + fc1 + GELU + fc2 + residual ----------------
__global__ __launch_bounds__(256,2) void swin_block_kernel(
    const float* __restrict__ x, const float* __restrict__ n1g, const float* __restrict__ n1b,
    const ushort* __restrict__ qkv_wt, const float* __restrict__ qkvb,
    const float* __restrict__ bias_tbl, const ushort* __restrict__ proj_wt,
    const float* __restrict__ projb,
    const float* __restrict__ n2g, const float* __restrict__ n2b,
    const ushort* __restrict__ fc1_wt, const float* __restrict__ fc1b,
    const ushort* __restrict__ fc2_wt, const float* __restrict__ fc2b,
    float* __restrict__ out)
{
  __shared__ ushort smem[SMEM_SZ];

  const int tid  = threadIdx.x;
  const int wave = tid >> 6;
  const int lane = tid & 63;
  const int b_   = blockIdx.x;
  const int b    = b_ >> 6;
  const int win  = b_ & 63;
  const int wi   = win >> 3, wj = win & 7;

  const int ncol  = lane & 15;
  const int quad  = lane >> 4;
  const int koff  = quad * 8;
  const int rbase = quad * 4;

  // ---- init ----
  for (int i = tid; i < NH*32*72; i += 256) smem[OFF_VT + i] = 0;
  for (int i = tid; i < 676; i += 256) smem[OFF_TBL + i] = f2bf(bias_tbl[i]);
  for (int i = tid; i < 15*136; i += 256) smem[OFF_BUFA + (49 + i/136)*136 + (i%136)] = 0;

  // ---- Phase 0: LN1 on gathered (shifted) window rows ----
  for (int r = wave; r < NTOK; r += 4){
    int ti = r / 7, tj = r % 7;
    int hh = (wi*7 + ti + SHIFT) % HIMG;
    int ww = (wj*7 + tj + SHIFT) % HIMG;
    size_t base = ((size_t)b * LTOK + hh*HIMG + ww) * DIM;
    int c = lane*2;
    float2 tv = *(const float2*)(x + base + c);
    float v0 = tv.x, v1 = tv.y;
    float mu = wred(v0 + v1) * (1.0f/128.0f);
    float d0 = v0-mu, d1 = v1-mu;
    float rstd = rsqrtf(wred(d0*d0 + d1*d1)*(1.0f/128.0f) + EPSF);
    smem[OFF_BUFA + r*136 + c]   = f2bf(d0*rstd*n1g[c]   + n1b[c]);
    smem[OFF_BUFA + r*136 + c+1] = f2bf(d1*rstd*n1g[c+1] + n1b[c+1]);
  }
  __syncthreads();

  // ---- Phase 1: QKV GEMM (64x384, K=128) ----
  {
    bf16x8 afrag[4][4];
    #pragma unroll
    for (int mt=0; mt<4; mt++)
      #pragma unroll
      for (int kb=0; kb<4; kb++)
        afrag[mt][kb] = *(const bf16x8*)&smem[OFF_BUFA + (mt*16 + ncol)*136 + kb*32 + koff];

    #pragma unroll
    for (int nt=0; nt<6; nt++){
      int c = wave*96 + nt*16 + ncol;
      int which = c >> 7, head = (c >> 5) & 3, d = c & 31;
      bf16x8 bfrag[4];
      #pragma unroll
      for (int kb=0; kb<4; kb++) bfrag[kb] = *(const bf16x8*)(qkv_wt + (size_t)c*128 + kb*32 + koff);
      float bias = qkvb[c];
      #pragma unroll
      for (int mt=0; mt<4; mt++){
        f32x4 acc = {0.f,0.f,0.f,0.f};
        #pragma unroll
        for (int kb=0; kb<4; kb++)
          acc = __builtin_amdgcn_mfma_f32_16x16x32_bf16(afrag[mt][kb], bfrag[kb], acc, 0,0,0);
        #pragma unroll
        for (int r=0; r<4; r++){
          int m = mt*16 + rbase + r;
          if (m < NTOK){
            ushort v = f2bf(acc[r] + bias);
            if (which == 2) smem[OFF_VT + (head*32 + d)*72 + m] = v;
            else            smem[OFF_QK + ((head*2 + which)*NTOK + m)*32 + d] = v;
          }
        }
      }
    }
  }
  __syncthreads();

  // ---- Phase 2: MFMA attention, wave = head ----
  {
    const int h = wave;
    const int qbase = OFF_QK + (h*2    )*NTOK*32;
    const int kbase = OFF_QK + (h*2 + 1)*NTOK*32;
    const int pbase = qbase;                       // P overlays Q+K region (dead after S)

    bf16x8 qf[4], kf[4];
    #pragma unroll
    for (int mt=0; mt<4; mt++) qf[mt] = *(const bf16x8*)&smem[qbase + (mt*16 + ncol)*32 + koff];
    #pragma unroll
    for (int nt=0; nt<4; nt++) kf[nt] = *(const bf16x8*)&smem[kbase + (nt*16 + ncol)*32 + koff];

    f32x4 s[4][4];
    #pragma unroll
    for (int mt=0; mt<4; mt++)
      #pragma unroll
      for (int nt=0; nt<4; nt++){
        f32x4 z = {0.f,0.f,0.f,0.f};
        s[mt][nt] = __builtin_amdgcn_mfma_f32_16x16x32_bf16(qf[mt], kf[nt], z, 0,0,0);
      }

    int kcol[4], rm[4];
    #pragma unroll
    for (int nt=0; nt<4; nt++){
      int k = nt*16 + ncol;
      kcol[nt] = k;
      int kc = k < NTOK ? k : 48;
      int si = kc/7, sj = kc%7;
      int sh = wi*7 + si, sw = wj*7 + sj;
      rm[nt] = (sh<49?0:(sh<53?1:2))*3 + (sw<49?0:(sw<53?1:2));
    }
    const float scale = 0.17677669529663687f;  // 1/sqrt(32)

    #pragma unroll
    for (int mt=0; mt<4; mt++){
      #pragma unroll
      for (int r=0; r<4; r++){
        int m  = mt*16 + rbase + r;
        int mc = m < NTOK ? m : 48;
        int ti = mc/7, tj = mc%7;
        int habs = wi*7 + ti, wabs = wj*7 + tj;
        int rn = (habs<49?0:(habs<53?1:2))*3 + (wabs<49?0:(wabs<53?1:2));
        float sv[4];
        #pragma unroll
        for (int nt=0; nt<4; nt++){
          int k  = kcol[nt];
          int kc = k < NTOK ? k : 48;
          int si = kc/7, sj = kc%7;
          int idx = (ti - si + 6)*13 + (tj - sj + 6);
          float bias = bf2f(smem[OFF_TBL + idx*4 + h]);
          float v = s[mt][nt][r]*scale + bias + (rn == rm[nt] ? 0.f : -100.f);
          sv[nt] = (k < NTOK) ? v : -1e30f;
        }
        float mx = fmaxf(fmaxf(sv[0],sv[1]), fmaxf(sv[2],sv[3]));
        #pragma unroll
        for (int off=1; off<16; off<<=1) mx = fmaxf(mx, __shfl_xor(mx, off, 64));
        float sum = 0.f;
        #pragma unroll
        for (int nt=0; nt<4; nt++){ sv[nt] = __expf(sv[nt]-mx); sum += sv[nt]; }
        #pragma unroll
        for (int off=1; off<16; off<<=1) sum += __shfl_xor(sum, off, 64);
        float rs = 1.0f/sum;
        #pragma unroll
        for (int nt=0; nt<4; nt++) s[mt][nt][r] = sv[nt]*rs;
      }
    }

    #pragma unroll
    for (int mt=0; mt<4; mt++)
      #pragma unroll
      for (int r=0; r<4; r++){
        int m = mt*16 + rbase + r;
        if (m < NTOK){
          #pragma unroll
          for (int nt=0; nt<4; nt++){
            int k = kcol[nt];
            if (k < 56) smem[pbase + m*56 + k] = f2bf(s[mt][nt][r]);
          }
        }
      }
    __builtin_amdgcn_s_waitcnt(0);

    bf16x8 vf[2][2], pf;
    #pragma unroll
    for (int nt=0; nt<2; nt++)
      #pragma unroll
      for (int kq=0; kq<2; kq++)
        vf[nt][kq] = *(const bf16x8*)&smem[OFF_VT + (h*32 + nt*16 + ncol)*72 + kq*32 + koff];

    f32x4 o[4][2];
    #pragma unroll
    for (int mt=0; mt<4; mt++)
      #pragma unroll
      for (int nt=0; nt<2; nt++){ f32x4 z={0.f,0.f,0.f,0.f}; o[mt][nt]=z; }

    #pragma unroll
    for (int mt=0; mt<4; mt++)
      #pragma unroll
      for (int kq=0; kq<2; kq++){
        pf = *(const bf16x8*)&smem[pbase + (mt*16 + ncol)*56 + kq*32 + koff];
        #pragma unroll
        for (int nt=0; nt<2; nt++)
          o[mt][nt] = __builtin_amdgcn_mfma_f32_16x16x32_bf16(pf, vf[nt][kq], o[mt][nt], 0,0,0);
      }

    #pragma unroll
    for (int mt=0; mt<4; mt++)
      #pragma unroll
      for (int nt=0; nt<2; nt++)
        #pragma unroll
        for (int r=0; r<4; r++){
          int m = mt*16 + rbase + r;
          if (m < NTOK)
            smem[OFF_BUFA + m*136 + h*32 + nt*16 + ncol] = f2bf(o[mt][nt][r]);
        }
  }
  __syncthreads();

  // ---- Phase 3: proj GEMM (64x128, K=128) + residual -> x2row in LDS (f32 [49][132]) ----
  float* x2row = (float*)&smem[OFF_QK];
  {
    bf16x8 afrag[4][4];
    #pragma unroll
    for (int mt=0; mt<4; mt++)
      #pragma unroll
      for (int kb=0; kb<4; kb++)
        afrag[mt][kb] = *(const bf16x8*)&smem[OFF_BUFA + (mt*16 + ncol)*136 + kb*32 + koff];

    #pragma unroll
    for (int nt=0; nt<2; nt++){
      int j = wave*32 + nt*16 + ncol;
      bf16x8 bfrag[4];
      #pragma unroll
      for (int kb=0; kb<4; kb++) bfrag[kb] = *(const bf16x8*)(proj_wt + (size_t)j*128 + kb*32 + koff);
      float bias = projb[j];
      #pragma unroll
      for (int mt=0; mt<4; mt++){
        f32x4 acc = {0.f,0.f,0.f,0.f};
        #pragma unroll
        for (int kb=0; kb<4; kb++)
          acc = __builtin_amdgcn_mfma_f32_16x16x32_bf16(afrag[mt][kb], bfrag[kb], acc, 0,0,0);
        #pragma unroll
        for (int r=0; r<4; r++){
          int m = mt*16 + rbase + r;
          if (m < NTOK){
            int ti = m/7, tj = m%7;
            int hh = (wi*7 + ti + SHIFT) % HIMG;
            int ww = (wj*7 + tj + SHIFT) % HIMG;
            size_t addr = ((size_t)b*LTOK + hh*HIMG + ww)*DIM + j;
            x2row[m*132 + j] = acc[r] + bias + x[addr];
          }
        }
      }
    }
  }
  __syncthreads();

  // ---- Phase 4: LN2 on x2row -> xn into bufA (rows 49-63 stay zero) ----
  for (int r = wave; r < NTOK; r += 4){
    int c = lane*2;
    float2 tv = *(const float2*)&x2row[r*132 + c];
    float v0 = tv.x, v1 = tv.y;
    float mu = wred(v0 + v1) * (1.0f/128.0f);
    float d0 = v0-mu, d1 = v1-mu;
    float rstd = rsqrtf(wred(d0*d0 + d1*d1)*(1.0f/128.0f) + EPSF);
    smem[OFF_BUFA + r*136 + c]   = f2bf(d0*rstd*n2g[c]   + n2b[c]);
    smem[OFF_BUFA + r*136 + c+1] = f2bf(d1*rstd*n2g[c+1] + n2b[c+1]);
  }
  __syncthreads();

  // ---- Phase 5: MLP tiled over 4 hidden chunks of 128 ----
  f32x4 o2[2][4];
  #pragma unroll
  for (int nt=0; nt<2; nt++)
    #pragma unroll
    for (int mt=0; mt<4; mt++){ f32x4 z={0.f,0.f,0.f,0.f}; o2[nt][mt]=z; }

  for (int hk=0; hk<4; hk++){
    // fc1 chunk: h[:, hk*128 + wave-cols] = GELU(xn @ W1 + b1)
    #pragma unroll
    for (int nt=0; nt<2; nt++){
      int cloc = wave*32 + nt*16 + ncol;        // col within chunk
      int c = hk*128 + cloc;                    // global hidden col
      bf16x8 bfrag[4];
      #pragma unroll
      for (int kb=0; kb<4; kb++)
        bfrag[kb] = *(const bf16x8*)(fc1_wt + (size_t)c*128 + kb*32 + koff);
      float bias = fc1b[c];
      #pragma unroll
      for (int mt=0; mt<4; mt++){
        f32x4 acc = {0.f,0.f,0.f,0.f};
        #pragma unroll
        for (int kb=0; kb<4; kb++){
          bf16x8 a = *(const bf16x8*)&smem[OFF_BUFA + (mt*16 + ncol)*136 + kb*32 + koff];
          acc = __builtin_amdgcn_mfma_f32_16x16x32_bf16(a, bfrag[kb], acc, 0,0,0);
        }
        #pragma unroll
        for (int r=0; r<4; r++){
          int m = mt*16 + rbase + r;
          float v = acc[r] + bias;
          float g = 0.5f*v*(1.0f + erff(v*0.70710678118654752f));
          smem[OFF_HCH + m*136 + cloc] = f2bf(g);
        }
      }
    }
    __syncthreads();

    // fc2 partial: out_acc += h_chunk @ W2[hk*128:, :]
    #pragma unroll
    for (int nt=0; nt<2; nt++){
      int j = wave*32 + nt*16 + ncol;
      bf16x8 bfrag[4];
      #pragma unroll
      for (int kb=0; kb<4; kb++)
        bfrag[kb] = *(const bf16x8*)(fc2_wt + (size_t)j*512 + hk*128 + kb*32 + koff);
      #pragma unroll
      for (int mt=0; mt<4; mt++){
        #pragma unroll
        for (int kb=0; kb<4; kb++){
          bf16x8 a = *(const bf16x8*)&smem[OFF_HCH + (mt*16 + ncol)*136 + kb*32 + koff];
          o2[nt][mt] = __builtin_amdgcn_mfma_f32_16x16x32_bf16(a, bfrag[kb], o2[nt][mt], 0,0,0);
        }
      }
    }
    __syncthreads();
  }

  // ---- Final: out = x2 + fc2 + b2, un-shift scatter (f32) ----
  #pragma unroll
  for (int nt=0; nt<2; nt++){
    int j = wave*32 + nt*16 + ncol;
    float bias = fc2b[j];
    #pragma unroll
    for (int mt=0; mt<4; mt++){
      #pragma unroll
      for (int r=0; r<4; r++){
        int m = mt*16 + rbase + r;
        if (m < NTOK){
          int ti = m/7, tj = m%7;
          int hh = (wi*7 + ti + SHIFT) % HIMG;
          int ww = (wj*7 + tj + SHIFT) % HIMG;
          size_t addr = ((size_t)b*LTOK + hh*HIMG + ww)*DIM + j;
          out[addr] = o2[nt][mt][r] + bias + x2row[m*132 + j];
        }
      }
    }
  }
}

extern "C" void kernel_launch(void* const* d_in, const int* in_sizes, int n_in,
                              void* d_out, int out_size, void* d_ws, size_t ws_size,
                              hipStream_t stream)
{
  const float* x    = (const float*)d_in[0];
  const float* n1g  = (const float*)d_in[1];
  const float* n1b  = (const float*)d_in[2];
  const float* qkvw = (const float*)d_in[3];
  const float* qkvb = (const float*)d_in[4];
  const float* tbl  = (const float*)d_in[5];
  const float* pw   = (const float*)d_in[6];
  const float* pb   = (const float*)d_in[7];
  const float* n2g  = (const float*)d_in[8];
  const float* n2b  = (const float*)d_in[9];
  const float* f1w  = (const float*)d_in[10];
  const float* f1b  = (const float*)d_in[11];
  const float* f2w  = (const float*)d_in[12];
  const float* f2b  = (const float*)d_in[13];

  // Workspace: transposed bf16 weights only (393,216 B).
  ushort* qkv_wt  = (ushort*)d_ws;            // [384][128]
  ushort* proj_wt = qkv_wt + 49152;           // [128][128]
  ushort* fc1_wt  = proj_wt + 16384;           // [512][128]
  ushort* fc2_wt  = fc1_wt + 65536;            // [128][512]

  transpose_cvt<<<(49152+255)/256, 256, 0, stream>>>(qkvw, qkv_wt, 128, 384);
  transpose_cvt<<<(16384+255)/256, 256, 0, stream>>>(pw,   proj_wt, 128, 128);
  transpose_cvt<<<(65536+255)/256, 256, 0, stream>>>(f1w,  fc1_wt, 128, 512);
  transpose_cvt<<<(65536+255)/256, 256, 0, stream>>>(f2w,  fc2_wt, 512, 128);

  swin_block_kernel<<<4096, 256, 0, stream>>>(x, n1g, n1b, qkv_wt, qkvb, tbl,
                                              proj_wt, pb, n2g, n2b,
                                              fc1_wt, f1b, fc2_wt, f2b,
                                              (float*)d_out);
}